// Round 11
// baseline (306.663 us; speedup 1.0000x reference)
//
#include <hip/hip_runtime.h>
#include <math.h>

#define N_ 8
#define L_ 1024
#define H_ 16
#define E_ 1024
#define D_ 64

typedef __bf16 bf16x8 __attribute__((ext_vector_type(8)));
typedef __bf16 bf16x4 __attribute__((ext_vector_type(4)));
typedef float  f32x4  __attribute__((ext_vector_type(4)));

#define MFMA16(a, b, c) __builtin_amdgcn_mfma_f32_16x16x32_bf16((a), (b), (c), 0, 0, 0)

// exp(s/32) == exp2(s * KSCALE) with KSCALE folded into K at projection time.
#define KSCALE 0.04508422002778011f   // log2(e)/32

// erbf padded with 80 zero rows: skew tail (t>1023 => S=0) falls out of the
// MFMA against zero rows -- no clamp, no select, no predication.
#define ER_ROWS 1104

// PS row stride: 68 elements (=34 words). Flash LDS = 54272 B => 3 blocks/CU
// (162816 <= 163840). Verified correct in r10 (passed, bank conflicts -35%).
#define PSS 68

// ---------------------------------------------------------------------------
// prep: Wo (1M) and Erel (64K) f32 -> bf16 scratch; zero-pad erbf tail rows.
// ---------------------------------------------------------------------------
__global__ __launch_bounds__(256) void prep_kernel(
    const float* __restrict__ Wo, const float* __restrict__ Erel,
    __bf16* __restrict__ wobf, __bf16* __restrict__ erbf)
{
    const int b = blockIdx.x;
    const int idx = b * 256 + threadIdx.x;
    if (b >= 1088) {                       // zero rows [1024, 1104)
        const int off = (idx - 1088 * 256) * 4;
        bf16x4 z; z[0] = z[1] = z[2] = z[3] = (__bf16)0.0f;
        *(bf16x4*)(erbf + 1024 * 64 + off) = z;
        return;
    }
    const float* src;
    __bf16* dst;
    int off;
    if (b < 1024) { src = Wo;   dst = wobf; off = idx * 4; }
    else          { src = Erel; dst = erbf; off = (idx - 1024 * 256) * 4; }
    const float4 f = *(const float4*)(src + off);
    bf16x4 h;
    h[0] = (__bf16)f.x; h[1] = (__bf16)f.y; h[2] = (__bf16)f.z; h[3] = (__bf16)f.w;
    *(bf16x4*)(dst + off) = h;
}

// ---------------------------------------------------------------------------
// qkv: x viewed as (131072 x 64) row-major (rows m=(n,l,h)); q/k/v = x @ W^T + b
// K pre-scaled by KSCALE. Epilogue via LDS transpose -> coalesced b128 stores.
// ---------------------------------------------------------------------------
__global__ __launch_bounds__(256) void qkv_kernel(
    const float* __restrict__ x,
    const float* __restrict__ Wq, const float* __restrict__ bq,
    const float* __restrict__ Wk, const float* __restrict__ bk,
    const float* __restrict__ Wv, const float* __restrict__ bv,
    __bf16* __restrict__ qo, __bf16* __restrict__ ko, __bf16* __restrict__ vo)
{
    const int t = threadIdx.x, w = t >> 6, lane = t & 63;
    const int quad = lane >> 4, l16 = lane & 15;
    const int m0 = blockIdx.x * 64;

    __shared__ __bf16 xs[64][72];
    __shared__ __bf16 wls[3][64][72];

    #pragma unroll
    for (int i = 0; i < 4; ++i) {
        const int idx = t + i * 256, row = idx >> 4, c4 = idx & 15;
        {
            const float4 f = *(const float4*)(x + (size_t)(m0 + row) * 64 + c4 * 4);
            bf16x4 hh; hh[0]=(__bf16)f.x; hh[1]=(__bf16)f.y; hh[2]=(__bf16)f.z; hh[3]=(__bf16)f.w;
            *(bf16x4*)&xs[row][c4 * 4] = hh;
        }
        {
            const float4 f = *(const float4*)(Wq + (size_t)row * 64 + c4 * 4);
            bf16x4 hh; hh[0]=(__bf16)f.x; hh[1]=(__bf16)f.y; hh[2]=(__bf16)f.z; hh[3]=(__bf16)f.w;
            *(bf16x4*)&wls[0][row][c4 * 4] = hh;
        }
        {
            const float4 f = *(const float4*)(Wk + (size_t)row * 64 + c4 * 4);
            bf16x4 hh; hh[0]=(__bf16)f.x; hh[1]=(__bf16)f.y; hh[2]=(__bf16)f.z; hh[3]=(__bf16)f.w;
            *(bf16x4*)&wls[1][row][c4 * 4] = hh;
        }
        {
            const float4 f = *(const float4*)(Wv + (size_t)row * 64 + c4 * 4);
            bf16x4 hh; hh[0]=(__bf16)f.x; hh[1]=(__bf16)f.y; hh[2]=(__bf16)f.z; hh[3]=(__bf16)f.w;
            *(bf16x4*)&wls[2][row][c4 * 4] = hh;
        }
    }
    __syncthreads();

    bf16x8 a[2];
    a[0] = *(const bf16x8*)&xs[w * 16 + l16][quad * 8];
    a[1] = *(const bf16x8*)&xs[w * 16 + l16][32 + quad * 8];

    f32x4 acc[12];
    const f32x4 zero4 = {0.f, 0.f, 0.f, 0.f};
    #pragma unroll
    for (int nt = 0; nt < 12; ++nt) acc[nt] = zero4;

    #pragma unroll
    for (int nt = 0; nt < 12; ++nt) {
        const int sel = nt >> 2, dt = nt & 3;
        #pragma unroll
        for (int c = 0; c < 2; ++c) {
            const bf16x8 b = *(const bf16x8*)&wls[sel][dt * 16 + l16][c * 32 + quad * 8];
            acc[nt] = MFMA16(a[c], b, acc[nt]);
        }
    }
    __syncthreads();   // wls reads done -> reuse as transpose staging

    __bf16* ts = &wls[0][0][0];
    const float* bias[3] = {bq, bk, bv};
    __bf16* outp[3] = {qo, ko, vo};
    #pragma unroll
    for (int nt = 0; nt < 12; ++nt) {
        const int sel = nt >> 2, dt = nt & 3;
        const float bb = bias[sel][dt * 16 + l16];
        const float scl = (sel == 1) ? KSCALE : 1.0f;
        #pragma unroll
        for (int r = 0; r < 4; ++r)
            ts[(size_t)(w * 16 + quad * 4 + r) * 208 + sel * 64 + dt * 16 + l16] =
                (__bf16)((acc[nt][r] + bb) * scl);
    }
    __syncthreads();
    #pragma unroll
    for (int sel = 0; sel < 3; ++sel)
        #pragma unroll
        for (int i = 0; i < 2; ++i) {
            const int idx = t * 2 + i, row = idx >> 3, c = idx & 7;
            *(float4*)(outp[sel] + (size_t)(m0 + row) * 64 + c * 8) =
                *(const float4*)&ts[(size_t)row * 208 + sel * 64 + c * 8];
        }
}

// ---------------------------------------------------------------------------
// vtr: v (n,l,h,d) -> vtr (n,h,d,l)  [64x64 tiles through LDS]
// ---------------------------------------------------------------------------
__global__ __launch_bounds__(256) void vtr_kernel(
    const __bf16* __restrict__ v, __bf16* __restrict__ vt)
{
    const int bid = blockIdx.x;
    const int lt = bid & 15, h = (bid >> 4) & 15, n = bid >> 8;
    const int l0 = lt * 64;
    const int t = threadIdx.x;
    __shared__ __bf16 ls[64][72];    // [d][l]

    const int lrow = t & 63, c0 = t >> 6;
    #pragma unroll
    for (int i = 0; i < 2; ++i) {
        const int c = c0 + i * 4;
        union { float4 f; __bf16 hv[8]; } u;
        u.f = *(const float4*)(v + ((size_t)(n * L_ + l0 + lrow) * H_ + h) * D_ + c * 8);
        #pragma unroll
        for (int j = 0; j < 8; ++j) ls[c * 8 + j][lrow] = u.hv[j];
    }
    __syncthreads();
    const int drow0 = t >> 3, lc = t & 7;
    #pragma unroll
    for (int i = 0; i < 2; ++i) {
        const int d = drow0 + i * 32;
        *(float4*)(vt + ((size_t)(n * H_ + h) * D_ + d) * L_ + l0 + lc * 8) =
            *(const float4*)&ls[d][lc * 8];
    }
}

// ---------------------------------------------------------------------------
// attn: block-specialized flash + rel. Grid 768 = 512 flash + 256 rel-PAIR
// blocks; LDS 54272 B (PSS=68, r10-verified) => EXACTLY 3 blocks/CU with no
// ragged tail generation (r10's 1024-grid @ 3-resident left a 256-block
// all-rel tail -- the suspected cause of its regression). Round-robin gives
// CU c bids {c, c+256, c+512} = 2 flash + 1 rel-pair: mixing preserved.
// Each rel block serially runs qt pair {3,0} or {2,1} (both 20 kt total);
// the loop body is the 5x-verified rel body, accumulators/Q reset per iter,
// V^T staging identical (depends only on (n,h)). Inter-iteration hazards:
// post-barrier epilogue touches RS+global only; next prologue touches
// VT+global only -- disjoint. VGPR must stay <=64 (the 32-waves/CU tier).
// DOUBLE-BUFFERED staging (single-buffer failed 2x -- banned).
// ---------------------------------------------------------------------------
__global__ __launch_bounds__(512, 4) void attn_kernel(
    const __bf16* __restrict__ qbf, const __bf16* __restrict__ kbf,
    const __bf16* __restrict__ vtrb, const __bf16* __restrict__ erbf,
    __bf16* __restrict__ attnA, __bf16* __restrict__ rbuf)
{
    __shared__ __bf16 smem[27136];     // 54272 B: flash KS|VT|PS ; rel VT|RS

    const int bid = blockIdx.x;
    const int t = threadIdx.x, w = t >> 6, lane = t & 63;
    const int quad = lane >> 4, l16 = lane & 15;
    const int srow = t >> 3, sc8 = (t & 7) * 8;
    const int erow = lane >> 3, ec8 = lane & 7;
    const f32x4 zero4 = {0.f, 0.f, 0.f, 0.f};

    if (bid < 512) {
        // ================= flash =================
        const int p = bid & 127;
        const int h = p & 15, n = p >> 4;
        const int qt = bid >> 7;
        const int q0 = qt * 256;
        __bf16* KS = smem;            // [2][64][72]
        __bf16* VT = smem + 9216;     // [2][64][72]
        __bf16* PS = smem + 18432;    // [128][PSS]

        const int qA = q0 + w * 16;   // sub-tile A first q row; B = qA + 128
        const size_t qoffA = ((size_t)(n * L_ + qA + l16) * H_ + h) * D_;
        const size_t qoffB = qoffA + (size_t)128 * H_ * D_;
        const bf16x8 qaA0 = *(const bf16x8*)(qbf + qoffA + quad * 8);
        const bf16x8 qaA1 = *(const bf16x8*)(qbf + qoffA + 32 + quad * 8);
        const bf16x8 qaB0 = *(const bf16x8*)(qbf + qoffB + quad * 8);
        const bf16x8 qaB1 = *(const bf16x8*)(qbf + qoffB + 32 + quad * 8);

        const __bf16* kbase = kbf + ((size_t)n * L_ * H_ + h) * D_;
        const __bf16* vbase = vtrb + ((size_t)(n * H_ + h) * D_) * L_;
        __bf16* ksst = KS + srow * 72 + sc8;
        __bf16* vtst = VT + srow * 72 + sc8;

        float4 kreg = *(const float4*)(kbase + (size_t)srow * 1024 + sc8);
        float4 vreg = *(const float4*)(vbase + (size_t)srow * 1024 + sc8);
        *(float4*)ksst = kreg;
        *(float4*)vtst = vreg;
        kreg = *(const float4*)(kbase + 64 * 1024 + (size_t)srow * 1024 + sc8);
        vreg = *(const float4*)(vbase + 64 + (size_t)srow * 1024 + sc8);
        __syncthreads();

        f32x4 OsA[4], OsB[4];
        #pragma unroll
        for (int nt = 0; nt < 4; ++nt) { OsA[nt] = zero4; OsB[nt] = zero4; }
        float esumA = 0.f, esumB = 0.f;
        __bf16* psrow = PS + (size_t)(w * 16 + l16) * PSS;

        for (int kt = 0; kt < 16; ++kt) {
            const int cur = kt & 1;
            if (kt < 15) {
                *(float4*)(ksst + (cur ^ 1) * 4608) = kreg;
                *(float4*)(vtst + (cur ^ 1) * 4608) = vreg;
                if (kt < 14) {
                    kreg = *(const float4*)(kbase + (size_t)(kt + 2) * 64 * 1024
                                            + (size_t)srow * 1024 + sc8);
                    vreg = *(const float4*)(vbase + (kt + 2) * 64
                                            + (size_t)srow * 1024 + sc8);
                }
            }
            const __bf16* ksc = KS + cur * 4608;
            const __bf16* vtc = VT + cur * 4608;

            // ---- S'^T for both sub-tiles, each K frag read once ----
            f32x4 sA[4], sB[4];
            #pragma unroll
            for (int nt = 0; nt < 4; ++nt) {
                const bf16x8 ka0 = *(const bf16x8*)&ksc[(nt * 16 + l16) * 72 + quad * 8];
                const bf16x8 ka1 = *(const bf16x8*)&ksc[(nt * 16 + l16) * 72 + 32 + quad * 8];
                f32x4 a = zero4;
                a = MFMA16(ka0, qaA0, a);
                a = MFMA16(ka1, qaA1, a);
                sA[nt] = a;
                f32x4 b = zero4;
                b = MFMA16(ka0, qaB0, b);
                b = MFMA16(ka1, qaB1, b);
                sB[nt] = b;
            }

            // ---- exp-P A -> PS, read A-frags; then B reusing the same rows ----
            #pragma unroll
            for (int nt = 0; nt < 4; ++nt) {
                bf16x4 pk;
                #pragma unroll
                for (int r = 0; r < 4; ++r) {
                    const float e = exp2f(sA[nt][r]);
                    esumA += e;
                    pk[r] = (__bf16)e;
                }
                *(bf16x4*)&psrow[nt * 16 + quad * 4] = pk;
            }
            const bf16x8 pbA0 = *(const bf16x8*)&psrow[quad * 8];
            const bf16x8 pbA1 = *(const bf16x8*)&psrow[32 + quad * 8];
            #pragma unroll
            for (int nt = 0; nt < 4; ++nt) {
                bf16x4 pk;
                #pragma unroll
                for (int r = 0; r < 4; ++r) {
                    const float e = exp2f(sB[nt][r]);
                    esumB += e;
                    pk[r] = (__bf16)e;
                }
                *(bf16x4*)&psrow[nt * 16 + quad * 4] = pk;
            }
            const bf16x8 pbB0 = *(const bf16x8*)&psrow[quad * 8];
            const bf16x8 pbB1 = *(const bf16x8*)&psrow[32 + quad * 8];

            // ---- PV: each V^T frag read once, used by both sub-tiles ----
            #pragma unroll
            for (int nt = 0; nt < 4; ++nt) {
                const bf16x8 va0 = *(const bf16x8*)&vtc[(nt * 16 + l16) * 72 + quad * 8];
                const bf16x8 va1 = *(const bf16x8*)&vtc[(nt * 16 + l16) * 72 + 32 + quad * 8];
                OsA[nt] = MFMA16(va0, pbA0, OsA[nt]);
                OsA[nt] = MFMA16(va1, pbA1, OsA[nt]);
                OsB[nt] = MFMA16(va0, pbB0, OsB[nt]);
                OsB[nt] = MFMA16(va1, pbB1, OsB[nt]);
            }
            __syncthreads();
        }

        // ---- epilogue: lsum reduce, assemble in PS, b128 stores ----
        esumA += __shfl_xor(esumA, 16, 64);
        esumA += __shfl_xor(esumA, 32, 64);
        esumB += __shfl_xor(esumB, 16, 64);
        esumB += __shfl_xor(esumB, 32, 64);
        const float invlA = 1.0f / esumA;
        const float invlB = 1.0f / esumB;

        #pragma unroll
        for (int nt = 0; nt < 4; ++nt) {
            bf16x4 ov;
            #pragma unroll
            for (int r = 0; r < 4; ++r) ov[r] = (__bf16)(OsA[nt][r] * invlA);
            *(bf16x4*)&psrow[nt * 16 + quad * 4] = ov;
        }
        #pragma unroll
        for (int i = 0; i < 2; ++i) {
            const int r = erow + i * 8;
            *(float4*)(attnA + ((size_t)(n * L_ + qA + r)) * E_ + h * 64 + ec8 * 8) =
                *(const float4*)&PS[(size_t)(w * 16 + r) * PSS + ec8 * 8];
        }
        #pragma unroll
        for (int nt = 0; nt < 4; ++nt) {
            bf16x4 ov;
            #pragma unroll
            for (int r = 0; r < 4; ++r) ov[r] = (__bf16)(OsB[nt][r] * invlB);
            *(bf16x4*)&psrow[nt * 16 + quad * 4] = ov;
        }
        #pragma unroll
        for (int i = 0; i < 2; ++i) {
            const int r = erow + i * 8;
            *(float4*)(attnA + ((size_t)(n * L_ + qA + 128 + r)) * E_ + h * 64 + ec8 * 8) =
                *(const float4*)&PS[(size_t)(w * 16 + r) * PSS + ec8 * 8];
        }
    } else {
        // ================= rel (two qt units per block) =================
        const int rid = bid - 512;            // [0,256)
        const int p = rid & 127;
        const int h = p & 15, n = p >> 4;
        const int psel = rid >> 7;            // 0: pair {3,0}; 1: pair {2,1}
        __bf16* VT = smem;            // [2][64][72]
        __bf16* RS = smem + 9216;     // [128][104]

        const __bf16* vbase = vtrb + ((size_t)(n * H_ + h) * D_) * L_;
        __bf16* vtst = VT + srow * 72 + sc8;
        __bf16* rsrow = RS + (size_t)(w * 16 + l16) * 104;

        #pragma unroll 1
        for (int it = 0; it < 2; ++it) {
            const int qt = (it == 0) ? (3 - psel) : psel;   // long first
            const int q0 = qt * 256;
            const int qA = q0 + w * 16;
            const size_t qoffA = ((size_t)(n * L_ + qA + l16) * H_ + h) * D_;
            const size_t qoffB = qoffA + (size_t)128 * H_ * D_;
            const bf16x8 qaA0 = *(const bf16x8*)(qbf + qoffA + quad * 8);
            const bf16x8 qaA1 = *(const bf16x8*)(qbf + qoffA + 32 + quad * 8);
            const bf16x8 qaB0 = *(const bf16x8*)(qbf + qoffB + quad * 8);
            const bf16x8 qaB1 = *(const bf16x8*)(qbf + qoffB + 32 + quad * 8);
            const int ktmax = qt * 4 + 4;

            float4 vreg = *(const float4*)(vbase + (size_t)srow * 1024 + sc8);
            *(float4*)vtst = vreg;
            vreg = *(const float4*)(vbase + 64 + (size_t)srow * 1024 + sc8);
            __syncthreads();

            f32x4 OrA[4], OrB[4];
            #pragma unroll
            for (int nt = 0; nt < 4; ++nt) { OrA[nt] = zero4; OrB[nt] = zero4; }

            for (int kt = 0; kt < ktmax; ++kt) {
                const int cur = kt & 1;
                if (kt + 1 < ktmax) {
                    *(float4*)(vtst + (cur ^ 1) * 4608) = vreg;
                    if (kt + 2 < ktmax)
                        vreg = *(const float4*)(vbase + (kt + 2) * 64
                                                + (size_t)srow * 1024 + sc8);
                }
                const __bf16* vtc = VT + cur * 4608;

                // branch-free skew: zero-padded erbf => unconditional b16
                // scatter. col = st*16 + quad*4 + r + l16 + 1 == 16 + kc;
                // slop cols [1,16)+[80,96) never read.
                const bool dorelA = (kt * 64 <= qA + 15);
                const bool dorelB = (kt * 64 <= qA + 143);  // dorelA => dorelB
                bf16x8 rbA0 = {}, rbA1 = {}, rbB0 = {}, rbB1 = {};
                if (dorelA) {
                    const int tb = kt * 64 + 1008 - qA;
                    #pragma unroll
                    for (int st = 0; st < 5; ++st) {
                        const __bf16* er = erbf + (size_t)(tb + st * 16 + l16) * 64;
                        f32x4 acc = zero4;
                        acc = MFMA16(*(const bf16x8*)(er + quad * 8), qaA0, acc);
                        acc = MFMA16(*(const bf16x8*)(er + 32 + quad * 8), qaA1, acc);
                        #pragma unroll
                        for (int r = 0; r < 4; ++r)
                            rsrow[st * 16 + quad * 4 + r + l16 + 1] = (__bf16)acc[r];
                    }
                    rbA0 = *(const bf16x8*)&rsrow[16 + quad * 8];
                    rbA1 = *(const bf16x8*)&rsrow[48 + quad * 8];
                }
                if (dorelB) {   // reuse the same RS rows (per-wave DS ordering)
                    const int tb = kt * 64 + 880 - qA;      // 1008 - (qA+128)
                    #pragma unroll
                    for (int st = 0; st < 5; ++st) {
                        const __bf16* er = erbf + (size_t)(tb + st * 16 + l16) * 64;
                        f32x4 acc = zero4;
                        acc = MFMA16(*(const bf16x8*)(er + quad * 8), qaB0, acc);
                        acc = MFMA16(*(const bf16x8*)(er + 32 + quad * 8), qaB1, acc);
                        #pragma unroll
                        for (int r = 0; r < 4; ++r)
                            rsrow[st * 16 + quad * 4 + r + l16 + 1] = (__bf16)acc[r];
                    }
                    rbB0 = *(const bf16x8*)&rsrow[16 + quad * 8];
                    rbB1 = *(const bf16x8*)&rsrow[48 + quad * 8];
                }

                // ---- PV: each V^T frag read once, used for both sub-tiles
                if (dorelA) {
                    #pragma unroll
                    for (int nt = 0; nt < 4; ++nt) {
                        const bf16x8 va0 = *(const bf16x8*)&vtc[(nt * 16 + l16) * 72 + quad * 8];
                        const bf16x8 va1 = *(const bf16x8*)&vtc[(nt * 16 + l16) * 72 + 32 + quad * 8];
                        OrA[nt] = MFMA16(va0, rbA0, OrA[nt]);
                        OrA[nt] = MFMA16(va1, rbA1, OrA[nt]);
                        OrB[nt] = MFMA16(va0, rbB0, OrB[nt]);
                        OrB[nt] = MFMA16(va1, rbB1, OrB[nt]);
                    }
                } else if (dorelB) {
                    #pragma unroll
                    for (int nt = 0; nt < 4; ++nt) {
                        const bf16x8 va0 = *(const bf16x8*)&vtc[(nt * 16 + l16) * 72 + quad * 8];
                        const bf16x8 va1 = *(const bf16x8*)&vtc[(nt * 16 + l16) * 72 + 32 + quad * 8];
                        OrB[nt] = MFMA16(va0, rbB0, OrB[nt]);
                        OrB[nt] = MFMA16(va1, rbB1, OrB[nt]);
                    }
                }
                __syncthreads();
            }

            // ---- epilogue: assemble in RS (wave-private), b128 stores ----
            #pragma unroll
            for (int nt = 0; nt < 4; ++nt) {
                bf16x4 ov;
                #pragma unroll
                for (int r = 0; r < 4; ++r) ov[r] = (__bf16)OrA[nt][r];
                *(bf16x4*)&rsrow[nt * 16 + quad * 4] = ov;
            }
            #pragma unroll
            for (int i = 0; i < 2; ++i) {
                const int r = erow + i * 8;
                *(float4*)(rbuf + ((size_t)(n * L_ + qA + r)) * E_ + h * 64 + ec8 * 8) =
                    *(const float4*)&RS[(size_t)(w * 16 + r) * 104 + ec8 * 8];
            }
            #pragma unroll
            for (int nt = 0; nt < 4; ++nt) {
                bf16x4 ov;
                #pragma unroll
                for (int r = 0; r < 4; ++r) ov[r] = (__bf16)OrB[nt][r];
                *(bf16x4*)&rsrow[nt * 16 + quad * 4] = ov;
            }
            #pragma unroll
            for (int i = 0; i < 2; ++i) {
                const int r = erow + i * 8;
                *(float4*)(rbuf + ((size_t)(n * L_ + qA + 128 + r)) * E_ + h * 64 + ec8 * 8) =
                    *(const float4*)&RS[(size_t)(w * 16 + r) * 104 + ec8 * 8];
            }
        }
    }
}

// ---------------------------------------------------------------------------
// addrel: attnA += rbuf (in place, bf16, b128). ~48 MB of traffic ~= 12 us;
// lets proj keep pure global_load_lds staging.
// ---------------------------------------------------------------------------
__global__ __launch_bounds__(256) void addrel_kernel(
    __bf16* __restrict__ attnA, const __bf16* __restrict__ rbuf)
{
    const size_t i = ((size_t)blockIdx.x * 256 + threadIdx.x) * 8;
    union { float4 f; __bf16 hv[8]; } ua, ur, uo;
    ua.f = *(const float4*)(attnA + i);
    ur.f = *(const float4*)(rbuf + i);
    #pragma unroll
    for (int j = 0; j < 8; ++j)
        uo.hv[j] = (__bf16)((float)ua.hv[j] + (float)ur.hv[j]);
    *(float4*)(attnA + i) = uo.f;
}

// ---------------------------------------------------------------------------
// proj: out (8192 x 1024) f32 = attnA (bf16) @ Wo^T (bf16) + bo.
// 128x128 C tile, BK=64, global_load_lds width-16 staging (round-0 form).
// ---------------------------------------------------------------------------
__global__ __launch_bounds__(256) void proj_kernel(
    const __bf16* __restrict__ A, const __bf16* __restrict__ W,
    const float* __restrict__ bo, float* __restrict__ out)
{
    const int bid = blockIdx.x;
    const int rt = bid >> 3, ct = bid & 7;
    const int r0 = rt * 128, c0 = ct * 128;
    const int t = threadIdx.x, w = t >> 6, lane = t & 63;
    const int quad = lane >> 4, l16 = lane & 15;
    const int wm = w >> 1, wn = w & 1;

    __shared__ __bf16 As[128 * 64];
    __shared__ __bf16 Bs[128 * 64];

    f32x4 acc[16];
    const f32x4 zero4 = {0.f, 0.f, 0.f, 0.f};
    #pragma unroll
    for (int i = 0; i < 16; ++i) acc[i] = zero4;

    const int lrow = lane >> 3, lcg = lane & 7;

    for (int kt = 0; kt < 16; ++kt) {
        const int e0 = kt * 64;
        __syncthreads();
        #pragma unroll
        for (int i = 0; i < 4; ++i) {
            const int chunk = w * 4 + i;
            const int row = chunk * 8 + lrow;
            const __bf16* ga = A + (size_t)(r0 + row) * E_ + e0 + lcg * 8;
            const __bf16* gb = W + (size_t)(c0 + row) * E_ + e0 + lcg * 8;
            __builtin_amdgcn_global_load_lds(
                (const __attribute__((address_space(1))) void*)ga,
                (__attribute__((address_space(3))) void*)&As[chunk * 512], 16, 0, 0);
            __builtin_amdgcn_global_load_lds(
                (const __attribute__((address_space(1))) void*)gb,
                (__attribute__((address_space(3))) void*)&Bs[chunk * 512], 16, 0, 0);
        }
        __syncthreads();
        #pragma unroll
        for (int c = 0; c < 2; ++c) {
            bf16x8 am[4], bn[4];
            #pragma unroll
            for (int i = 0; i < 4; ++i) {
                am[i] = *(const bf16x8*)&As[(wm * 64 + i * 16 + l16) * 64 + c * 32 + quad * 8];
                bn[i] = *(const bf16x8*)&Bs[(wn * 64 + i * 16 + l16) * 64 + c * 32 + quad * 8];
            }
            #pragma unroll
            for (int i = 0; i < 4; ++i)
                #pragma unroll
                for (int j = 0; j < 4; ++j)
                    acc[i * 4 + j] = MFMA16(am[i], bn[j], acc[i * 4 + j]);
        }
    }

    #pragma unroll
    for (int i = 0; i < 4; ++i)
        #pragma unroll
        for (int j = 0; j < 4; ++j) {
            const int col = c0 + wn * 64 + j * 16 + l16;
            const float bb = bo[col];
            #pragma unroll
            for (int r = 0; r < 4; ++r)
                out[(size_t)(r0 + wm * 64 + i * 16 + quad * 4 + r) * E_ + col] =
                    acc[i * 4 + j][r] + bb;
        }
}

// ---------------------------------------------------------------------------
extern "C" void kernel_launch(void* const* d_in, const int* in_sizes, int n_in,
                              void* d_out, int out_size, void* d_ws, size_t ws_size,
                              hipStream_t stream)
{
    const float* x    = (const float*)d_in[0];
    const float* Wq   = (const float*)d_in[1];
    const float* bq   = (const float*)d_in[2];
    const float* Wk   = (const float*)d_in[3];
    const float* bk   = (const float*)d_in[4];
    const float* Wv   = (const float*)d_in[5];
    const float* bv   = (const float*)d_in[6];
    const float* Erel = (const float*)d_in[7];
    const float* Wo   = (const float*)d_in[8];
    const float* bo   = (const float*)d_in[9];
    float* out = (float*)d_out;

    char* p = (char*)d_ws;
    __bf16* qbf   = (__bf16*)p; p += (size_t)N_ * L_ * H_ * D_ * 2;  // 16 MB
    __bf16* kbf   = (__bf16*)p; p += (size_t)N_ * L_ * H_ * D_ * 2;  // scaled K
    __bf16* vbf   = (__bf16*)p; p += (size_t)N_ * L_ * H_ * D_ * 2;
    __bf16* vtrb  = (__bf16*)p; p += (size_t)N_ * L_ * H_ * D_ * 2;  // V^T
    __bf16* attnA = (__bf16*)p; p += (size_t)N_ * L_ * E_ * 2;       // 16 MB
    __bf16* rbuf  = (__bf16*)p; p += (size_t)N_ * L_ * E_ * 2;       // 16 MB
    __bf16* wobf  = (__bf16*)p; p += (size_t)E_ * E_ * 2;            // 2 MB
    __bf16* erbf  = (__bf16*)p; p += (size_t)ER_ROWS * D_ * 2;       // 138 KB (padded)

    prep_kernel<<<1093, 256, 0, stream>>>(Wo, Erel, wobf, erbf);
    qkv_kernel<<<(N_ * L_ * H_) / 64, 256, 0, stream>>>(x, Wq, bq, Wk, bk, Wv, bv,
                                                        qbf, kbf, vbf);
    vtr_kernel<<<N_ * H_ * (L_ / 64), 256, 0, stream>>>(vbf, vtrb);
    attn_kernel<<<768, 512, 0, stream>>>(qbf, kbf, vtrb, erbf, attnA, rbuf);
    addrel_kernel<<<4096, 256, 0, stream>>>(attnA, rbuf);
    proj_kernel<<<(N_ * L_ / 128) * (E_ / 128), 256, 0, stream>>>(attnA, wobf, bo, out);
}

// Round 12
// 277.165 us; speedup vs baseline: 1.1064x; 1.1064x over previous
//
#include <hip/hip_runtime.h>
#include <math.h>

#define N_ 8
#define L_ 1024
#define H_ 16
#define E_ 1024
#define D_ 64

typedef __bf16 bf16x8 __attribute__((ext_vector_type(8)));
typedef __bf16 bf16x4 __attribute__((ext_vector_type(4)));
typedef float  f32x4  __attribute__((ext_vector_type(4)));

#define MFMA16(a, b, c) __builtin_amdgcn_mfma_f32_16x16x32_bf16((a), (b), (c), 0, 0, 0)

// exp(s/32) == exp2(s * KSCALE) with KSCALE folded into K at projection time.
#define KSCALE 0.04508422002778011f   // log2(e)/32

// erbf padded with 80 zero rows: skew tail (t>1023 => S=0) falls out of the
// MFMA against zero rows -- no clamp, no select, no predication.
#define ER_ROWS 1104

// ---------------------------------------------------------------------------
// prep: Wo (1M) and Erel (64K) f32 -> bf16 scratch; zero-pad erbf tail rows.
// ---------------------------------------------------------------------------
__global__ __launch_bounds__(256) void prep_kernel(
    const float* __restrict__ Wo, const float* __restrict__ Erel,
    __bf16* __restrict__ wobf, __bf16* __restrict__ erbf)
{
    const int b = blockIdx.x;
    const int idx = b * 256 + threadIdx.x;
    if (b >= 1088) {                       // zero rows [1024, 1104)
        const int off = (idx - 1088 * 256) * 4;
        bf16x4 z; z[0] = z[1] = z[2] = z[3] = (__bf16)0.0f;
        *(bf16x4*)(erbf + 1024 * 64 + off) = z;
        return;
    }
    const float* src;
    __bf16* dst;
    int off;
    if (b < 1024) { src = Wo;   dst = wobf; off = idx * 4; }
    else          { src = Erel; dst = erbf; off = (idx - 1024 * 256) * 4; }
    const float4 f = *(const float4*)(src + off);
    bf16x4 h;
    h[0] = (__bf16)f.x; h[1] = (__bf16)f.y; h[2] = (__bf16)f.z; h[3] = (__bf16)f.w;
    *(bf16x4*)(dst + off) = h;
}

// ---------------------------------------------------------------------------
// qkv: x viewed as (131072 x 64) row-major (rows m=(n,l,h)); q/k/v = x @ W^T + b
// K pre-scaled by KSCALE. Epilogue via LDS transpose -> coalesced b128 stores.
// ---------------------------------------------------------------------------
__global__ __launch_bounds__(256) void qkv_kernel(
    const float* __restrict__ x,
    const float* __restrict__ Wq, const float* __restrict__ bq,
    const float* __restrict__ Wk, const float* __restrict__ bk,
    const float* __restrict__ Wv, const float* __restrict__ bv,
    __bf16* __restrict__ qo, __bf16* __restrict__ ko, __bf16* __restrict__ vo)
{
    const int t = threadIdx.x, w = t >> 6, lane = t & 63;
    const int quad = lane >> 4, l16 = lane & 15;
    const int m0 = blockIdx.x * 64;

    __shared__ __bf16 xs[64][72];
    __shared__ __bf16 wls[3][64][72];

    #pragma unroll
    for (int i = 0; i < 4; ++i) {
        const int idx = t + i * 256, row = idx >> 4, c4 = idx & 15;
        {
            const float4 f = *(const float4*)(x + (size_t)(m0 + row) * 64 + c4 * 4);
            bf16x4 hh; hh[0]=(__bf16)f.x; hh[1]=(__bf16)f.y; hh[2]=(__bf16)f.z; hh[3]=(__bf16)f.w;
            *(bf16x4*)&xs[row][c4 * 4] = hh;
        }
        {
            const float4 f = *(const float4*)(Wq + (size_t)row * 64 + c4 * 4);
            bf16x4 hh; hh[0]=(__bf16)f.x; hh[1]=(__bf16)f.y; hh[2]=(__bf16)f.z; hh[3]=(__bf16)f.w;
            *(bf16x4*)&wls[0][row][c4 * 4] = hh;
        }
        {
            const float4 f = *(const float4*)(Wk + (size_t)row * 64 + c4 * 4);
            bf16x4 hh; hh[0]=(__bf16)f.x; hh[1]=(__bf16)f.y; hh[2]=(__bf16)f.z; hh[3]=(__bf16)f.w;
            *(bf16x4*)&wls[1][row][c4 * 4] = hh;
        }
        {
            const float4 f = *(const float4*)(Wv + (size_t)row * 64 + c4 * 4);
            bf16x4 hh; hh[0]=(__bf16)f.x; hh[1]=(__bf16)f.y; hh[2]=(__bf16)f.z; hh[3]=(__bf16)f.w;
            *(bf16x4*)&wls[2][row][c4 * 4] = hh;
        }
    }
    __syncthreads();

    bf16x8 a[2];
    a[0] = *(const bf16x8*)&xs[w * 16 + l16][quad * 8];
    a[1] = *(const bf16x8*)&xs[w * 16 + l16][32 + quad * 8];

    f32x4 acc[12];
    const f32x4 zero4 = {0.f, 0.f, 0.f, 0.f};
    #pragma unroll
    for (int nt = 0; nt < 12; ++nt) acc[nt] = zero4;

    #pragma unroll
    for (int nt = 0; nt < 12; ++nt) {
        const int sel = nt >> 2, dt = nt & 3;
        #pragma unroll
        for (int c = 0; c < 2; ++c) {
            const bf16x8 b = *(const bf16x8*)&wls[sel][dt * 16 + l16][c * 32 + quad * 8];
            acc[nt] = MFMA16(a[c], b, acc[nt]);
        }
    }
    __syncthreads();   // wls reads done -> reuse as transpose staging

    __bf16* ts = &wls[0][0][0];
    const float* bias[3] = {bq, bk, bv};
    __bf16* outp[3] = {qo, ko, vo};
    #pragma unroll
    for (int nt = 0; nt < 12; ++nt) {
        const int sel = nt >> 2, dt = nt & 3;
        const float bb = bias[sel][dt * 16 + l16];
        const float scl = (sel == 1) ? KSCALE : 1.0f;
        #pragma unroll
        for (int r = 0; r < 4; ++r)
            ts[(size_t)(w * 16 + quad * 4 + r) * 208 + sel * 64 + dt * 16 + l16] =
                (__bf16)((acc[nt][r] + bb) * scl);
    }
    __syncthreads();
    #pragma unroll
    for (int sel = 0; sel < 3; ++sel)
        #pragma unroll
        for (int i = 0; i < 2; ++i) {
            const int idx = t * 2 + i, row = idx >> 3, c = idx & 7;
            *(float4*)(outp[sel] + (size_t)(m0 + row) * 64 + c * 8) =
                *(const float4*)&ts[(size_t)row * 208 + sel * 64 + c * 8];
        }
}

// ---------------------------------------------------------------------------
// vtr: v (n,l,h,d) -> vtr (n,h,d,l)  [64x64 tiles through LDS]
// ---------------------------------------------------------------------------
__global__ __launch_bounds__(256) void vtr_kernel(
    const __bf16* __restrict__ v, __bf16* __restrict__ vt)
{
    const int bid = blockIdx.x;
    const int lt = bid & 15, h = (bid >> 4) & 15, n = bid >> 8;
    const int l0 = lt * 64;
    const int t = threadIdx.x;
    __shared__ __bf16 ls[64][72];    // [d][l]

    const int lrow = t & 63, c0 = t >> 6;
    #pragma unroll
    for (int i = 0; i < 2; ++i) {
        const int c = c0 + i * 4;
        union { float4 f; __bf16 hv[8]; } u;
        u.f = *(const float4*)(v + ((size_t)(n * L_ + l0 + lrow) * H_ + h) * D_ + c * 8);
        #pragma unroll
        for (int j = 0; j < 8; ++j) ls[c * 8 + j][lrow] = u.hv[j];
    }
    __syncthreads();
    const int drow0 = t >> 3, lc = t & 7;
    #pragma unroll
    for (int i = 0; i < 2; ++i) {
        const int d = drow0 + i * 32;
        *(float4*)(vt + ((size_t)(n * H_ + h) * D_ + d) * L_ + l0 + lc * 8) =
            *(const float4*)&ls[d][lc * 8];
    }
}

// ---------------------------------------------------------------------------
// attn: block-specialized flash + rel, r9 base (best: attn 141 us, passed).
// Occupancy lever REFUTED (r10: 3/CU LDS-diet 149.6; r11: 768-grid 166.6) --
// 2 blocks/CU is optimal; latency must be cut inside the wave. This round:
// (1) manual V^T fragment prefetch in flash's PV path. The allocator sat at
//     64 VGPR (8-wave/EU tier) but LDS caps residency at 2 blocks = 4
//     waves/EU, where the budget is 128 VGPR -- free headroom. va frags are
//     4 VGPR each; hoisting nt=0,1 reads before the exp phase and nt=2,3
//     after the pbA read gives them 200+ cy to land (PV's first MFMA
//     previously ate ~120 cy of LDS latency per nt).
// (2) esum accumulated into f32x4 (4 independent FADD chains, depth 4) vs a
//     32-deep serial chain per kt; reduced at epilogue.
// rel path and all sync structure byte-identical to r9.
// ---------------------------------------------------------------------------
__global__ __launch_bounds__(512, 4) void attn_kernel(
    const __bf16* __restrict__ qbf, const __bf16* __restrict__ kbf,
    const __bf16* __restrict__ vtrb, const __bf16* __restrict__ erbf,
    __bf16* __restrict__ attnA, __bf16* __restrict__ rbuf)
{
    __shared__ __bf16 smem[27648];     // flash: KS|VT|PS ; rel: VT|RS

    const int bid = blockIdx.x;
    const int isrel = (bid >> 8) & 1;
    const int vid = (bid & 255) | ((bid >> 9) << 8);   // [0,512) per type

    const int t = threadIdx.x, w = t >> 6, lane = t & 63;
    const int quad = lane >> 4, l16 = lane & 15;
    const int p = vid & 127;                  // (n,h) stable across qt
    const int h = p & 15, n = p >> 4;
    const int srow = t >> 3, sc8 = (t & 7) * 8;
    const int erow = lane >> 3, ec8 = lane & 7;
    const f32x4 zero4 = {0.f, 0.f, 0.f, 0.f};

    if (!isrel) {
        // ================= flash =================
        const int qt = vid >> 7;
        const int q0 = qt * 256;
        __bf16* KS = smem;            // [2][64][72]
        __bf16* VT = smem + 9216;     // [2][64][72]
        __bf16* PS = smem + 18432;    // [128][72]

        const int qA = q0 + w * 16;   // sub-tile A first q row; B = qA + 128
        const size_t qoffA = ((size_t)(n * L_ + qA + l16) * H_ + h) * D_;
        const size_t qoffB = qoffA + (size_t)128 * H_ * D_;
        const bf16x8 qaA0 = *(const bf16x8*)(qbf + qoffA + quad * 8);
        const bf16x8 qaA1 = *(const bf16x8*)(qbf + qoffA + 32 + quad * 8);
        const bf16x8 qaB0 = *(const bf16x8*)(qbf + qoffB + quad * 8);
        const bf16x8 qaB1 = *(const bf16x8*)(qbf + qoffB + 32 + quad * 8);

        const __bf16* kbase = kbf + ((size_t)n * L_ * H_ + h) * D_;
        const __bf16* vbase = vtrb + ((size_t)(n * H_ + h) * D_) * L_;
        __bf16* ksst = KS + srow * 72 + sc8;
        __bf16* vtst = VT + srow * 72 + sc8;

        float4 kreg = *(const float4*)(kbase + (size_t)srow * 1024 + sc8);
        float4 vreg = *(const float4*)(vbase + (size_t)srow * 1024 + sc8);
        *(float4*)ksst = kreg;
        *(float4*)vtst = vreg;
        kreg = *(const float4*)(kbase + 64 * 1024 + (size_t)srow * 1024 + sc8);
        vreg = *(const float4*)(vbase + 64 + (size_t)srow * 1024 + sc8);
        __syncthreads();

        f32x4 OsA[4], OsB[4];
        #pragma unroll
        for (int nt = 0; nt < 4; ++nt) { OsA[nt] = zero4; OsB[nt] = zero4; }
        f32x4 esumvA = zero4, esumvB = zero4;
        __bf16* psrow = PS + (size_t)(w * 16 + l16) * 72;

        for (int kt = 0; kt < 16; ++kt) {
            const int cur = kt & 1;
            if (kt < 15) {
                *(float4*)(ksst + (cur ^ 1) * 4608) = kreg;
                *(float4*)(vtst + (cur ^ 1) * 4608) = vreg;
                if (kt < 14) {
                    kreg = *(const float4*)(kbase + (size_t)(kt + 2) * 64 * 1024
                                            + (size_t)srow * 1024 + sc8);
                    vreg = *(const float4*)(vbase + (kt + 2) * 64
                                            + (size_t)srow * 1024 + sc8);
                }
            }
            const __bf16* ksc = KS + cur * 4608;
            const __bf16* vtc = VT + cur * 4608;

            // ---- S'^T for both sub-tiles, each K frag read once ----
            f32x4 sA[4], sB[4];
            #pragma unroll
            for (int nt = 0; nt < 4; ++nt) {
                const bf16x8 ka0 = *(const bf16x8*)&ksc[(nt * 16 + l16) * 72 + quad * 8];
                const bf16x8 ka1 = *(const bf16x8*)&ksc[(nt * 16 + l16) * 72 + 32 + quad * 8];
                f32x4 a = zero4;
                a = MFMA16(ka0, qaA0, a);
                a = MFMA16(ka1, qaA1, a);
                sA[nt] = a;
                f32x4 b = zero4;
                b = MFMA16(ka0, qaB0, b);
                b = MFMA16(ka1, qaB1, b);
                sB[nt] = b;
            }

            // ---- early V^T frag reads for nt=0,1 (land during exp phase) ----
            const bf16x8 va00 = *(const bf16x8*)&vtc[(0 * 16 + l16) * 72 + quad * 8];
            const bf16x8 va01 = *(const bf16x8*)&vtc[(0 * 16 + l16) * 72 + 32 + quad * 8];
            const bf16x8 va10 = *(const bf16x8*)&vtc[(1 * 16 + l16) * 72 + quad * 8];
            const bf16x8 va11 = *(const bf16x8*)&vtc[(1 * 16 + l16) * 72 + 32 + quad * 8];

            // ---- exp-P A -> PS, read A-frags; then B reusing the same rows ----
            #pragma unroll
            for (int nt = 0; nt < 4; ++nt) {
                bf16x4 pk;
                #pragma unroll
                for (int r = 0; r < 4; ++r) {
                    const float e = exp2f(sA[nt][r]);
                    esumvA[r] += e;
                    pk[r] = (__bf16)e;
                }
                *(bf16x4*)&psrow[nt * 16 + quad * 4] = pk;
            }
            const bf16x8 pbA0 = *(const bf16x8*)&psrow[quad * 8];
            const bf16x8 pbA1 = *(const bf16x8*)&psrow[32 + quad * 8];
            // ---- early V^T frag reads for nt=2,3 (land during exp-B) ----
            const bf16x8 va20 = *(const bf16x8*)&vtc[(2 * 16 + l16) * 72 + quad * 8];
            const bf16x8 va21 = *(const bf16x8*)&vtc[(2 * 16 + l16) * 72 + 32 + quad * 8];
            #pragma unroll
            for (int nt = 0; nt < 4; ++nt) {
                bf16x4 pk;
                #pragma unroll
                for (int r = 0; r < 4; ++r) {
                    const float e = exp2f(sB[nt][r]);
                    esumvB[r] += e;
                    pk[r] = (__bf16)e;
                }
                *(bf16x4*)&psrow[nt * 16 + quad * 4] = pk;
            }
            const bf16x8 pbB0 = *(const bf16x8*)&psrow[quad * 8];
            const bf16x8 pbB1 = *(const bf16x8*)&psrow[32 + quad * 8];
            const bf16x8 va30 = *(const bf16x8*)&vtc[(3 * 16 + l16) * 72 + quad * 8];
            const bf16x8 va31 = *(const bf16x8*)&vtc[(3 * 16 + l16) * 72 + 32 + quad * 8];

            // ---- PV: operands pre-loaded; both sub-tiles per frag ----
            OsA[0] = MFMA16(va00, pbA0, OsA[0]);
            OsA[0] = MFMA16(va01, pbA1, OsA[0]);
            OsB[0] = MFMA16(va00, pbB0, OsB[0]);
            OsB[0] = MFMA16(va01, pbB1, OsB[0]);
            OsA[1] = MFMA16(va10, pbA0, OsA[1]);
            OsA[1] = MFMA16(va11, pbA1, OsA[1]);
            OsB[1] = MFMA16(va10, pbB0, OsB[1]);
            OsB[1] = MFMA16(va11, pbB1, OsB[1]);
            OsA[2] = MFMA16(va20, pbA0, OsA[2]);
            OsA[2] = MFMA16(va21, pbA1, OsA[2]);
            OsB[2] = MFMA16(va20, pbB0, OsB[2]);
            OsB[2] = MFMA16(va21, pbB1, OsB[2]);
            OsA[3] = MFMA16(va30, pbA0, OsA[3]);
            OsA[3] = MFMA16(va31, pbA1, OsA[3]);
            OsB[3] = MFMA16(va30, pbB0, OsB[3]);
            OsB[3] = MFMA16(va31, pbB1, OsB[3]);
            __syncthreads();
        }

        // ---- epilogue: lsum reduce, assemble in PS, b128 stores ----
        float esumA = (esumvA[0] + esumvA[1]) + (esumvA[2] + esumvA[3]);
        float esumB = (esumvB[0] + esumvB[1]) + (esumvB[2] + esumvB[3]);
        esumA += __shfl_xor(esumA, 16, 64);
        esumA += __shfl_xor(esumA, 32, 64);
        esumB += __shfl_xor(esumB, 16, 64);
        esumB += __shfl_xor(esumB, 32, 64);
        const float invlA = 1.0f / esumA;
        const float invlB = 1.0f / esumB;

        #pragma unroll
        for (int nt = 0; nt < 4; ++nt) {
            bf16x4 ov;
            #pragma unroll
            for (int r = 0; r < 4; ++r) ov[r] = (__bf16)(OsA[nt][r] * invlA);
            *(bf16x4*)&psrow[nt * 16 + quad * 4] = ov;
        }
        #pragma unroll
        for (int i = 0; i < 2; ++i) {
            const int r = erow + i * 8;
            *(float4*)(attnA + ((size_t)(n * L_ + qA + r)) * E_ + h * 64 + ec8 * 8) =
                *(const float4*)&PS[(size_t)(w * 16 + r) * 72 + ec8 * 8];
        }
        #pragma unroll
        for (int nt = 0; nt < 4; ++nt) {
            bf16x4 ov;
            #pragma unroll
            for (int r = 0; r < 4; ++r) ov[r] = (__bf16)(OsB[nt][r] * invlB);
            *(bf16x4*)&psrow[nt * 16 + quad * 4] = ov;
        }
        #pragma unroll
        for (int i = 0; i < 2; ++i) {
            const int r = erow + i * 8;
            *(float4*)(attnA + ((size_t)(n * L_ + qA + 128 + r)) * E_ + h * 64 + ec8 * 8) =
                *(const float4*)&PS[(size_t)(w * 16 + r) * 72 + ec8 * 8];
        }
    } else {
        // ================= rel =================
        const int qt = 3 - (vid >> 7);        // descending length: long blocks first
        const int q0 = qt * 256;
        __bf16* VT = smem;            // [2][64][72]
        __bf16* RS = smem + 9216;     // [128][104]

        const int qA = q0 + w * 16;
        const size_t qoffA = ((size_t)(n * L_ + qA + l16) * H_ + h) * D_;
        const size_t qoffB = qoffA + (size_t)128 * H_ * D_;
        const bf16x8 qaA0 = *(const bf16x8*)(qbf + qoffA + quad * 8);
        const bf16x8 qaA1 = *(const bf16x8*)(qbf + qoffA + 32 + quad * 8);
        const bf16x8 qaB0 = *(const bf16x8*)(qbf + qoffB + quad * 8);
        const bf16x8 qaB1 = *(const bf16x8*)(qbf + qoffB + 32 + quad * 8);

        const __bf16* vbase = vtrb + ((size_t)(n * H_ + h) * D_) * L_;
        __bf16* vtst = VT + srow * 72 + sc8;
        const int ktmax = qt * 4 + 4;

        float4 vreg = *(const float4*)(vbase + (size_t)srow * 1024 + sc8);
        *(float4*)vtst = vreg;
        vreg = *(const float4*)(vbase + 64 + (size_t)srow * 1024 + sc8);
        __syncthreads();

        f32x4 OrA[4], OrB[4];
        #pragma unroll
        for (int nt = 0; nt < 4; ++nt) { OrA[nt] = zero4; OrB[nt] = zero4; }
        __bf16* rsrow = RS + (size_t)(w * 16 + l16) * 104;

        for (int kt = 0; kt < ktmax; ++kt) {
            const int cur = kt & 1;
            if (kt + 1 < ktmax) {
                *(float4*)(vtst + (cur ^ 1) * 4608) = vreg;
                if (kt + 2 < ktmax)
                    vreg = *(const float4*)(vbase + (kt + 2) * 64
                                            + (size_t)srow * 1024 + sc8);
            }
            const __bf16* vtc = VT + cur * 4608;

            // branch-free skew: zero-padded erbf => unconditional b16 scatter.
            // col = st*16 + quad*4 + r + l16 + 1 == 16 + kc; slop cols
            // [1,16)+[80,96) never read; each (row,col) written exactly once.
            const bool dorelA = (kt * 64 <= qA + 15);
            const bool dorelB = (kt * 64 <= qA + 143);   // dorelA implies dorelB
            bf16x8 rbA0 = {}, rbA1 = {}, rbB0 = {}, rbB1 = {};
            if (dorelA) {
                const int tb = kt * 64 + 1008 - qA;
                #pragma unroll
                for (int st = 0; st < 5; ++st) {
                    const __bf16* er = erbf + (size_t)(tb + st * 16 + l16) * 64;
                    f32x4 acc = zero4;
                    acc = MFMA16(*(const bf16x8*)(er + quad * 8), qaA0, acc);
                    acc = MFMA16(*(const bf16x8*)(er + 32 + quad * 8), qaA1, acc);
                    #pragma unroll
                    for (int r = 0; r < 4; ++r)
                        rsrow[st * 16 + quad * 4 + r + l16 + 1] = (__bf16)acc[r];
                }
                rbA0 = *(const bf16x8*)&rsrow[16 + quad * 8];
                rbA1 = *(const bf16x8*)&rsrow[48 + quad * 8];
            }
            if (dorelB) {   // reuse the same RS rows (per-wave DS ordering)
                const int tb = kt * 64 + 880 - qA;       // 1008 - (qA+128)
                #pragma unroll
                for (int st = 0; st < 5; ++st) {
                    const __bf16* er = erbf + (size_t)(tb + st * 16 + l16) * 64;
                    f32x4 acc = zero4;
                    acc = MFMA16(*(const bf16x8*)(er + quad * 8), qaB0, acc);
                    acc = MFMA16(*(const bf16x8*)(er + 32 + quad * 8), qaB1, acc);
                    #pragma unroll
                    for (int r = 0; r < 4; ++r)
                        rsrow[st * 16 + quad * 4 + r + l16 + 1] = (__bf16)acc[r];
                }
                rbB0 = *(const bf16x8*)&rsrow[16 + quad * 8];
                rbB1 = *(const bf16x8*)&rsrow[48 + quad * 8];
            }

            // ---- PV: each V^T frag read once, used for both sub-tiles ----
            if (dorelA) {
                #pragma unroll
                for (int nt = 0; nt < 4; ++nt) {
                    const bf16x8 va0 = *(const bf16x8*)&vtc[(nt * 16 + l16) * 72 + quad * 8];
                    const bf16x8 va1 = *(const bf16x8*)&vtc[(nt * 16 + l16) * 72 + 32 + quad * 8];
                    OrA[nt] = MFMA16(va0, rbA0, OrA[nt]);
                    OrA[nt] = MFMA16(va1, rbA1, OrA[nt]);
                    OrB[nt] = MFMA16(va0, rbB0, OrB[nt]);
                    OrB[nt] = MFMA16(va1, rbB1, OrB[nt]);
                }
            } else if (dorelB) {
                #pragma unroll
                for (int nt = 0; nt < 4; ++nt) {
                    const bf16x8 va0 = *(const bf16x8*)&vtc[(nt * 16 + l16) * 72 + quad * 8];
                    const bf16x8 va1 = *(const bf16x8*)&vtc[(nt * 16 + l16) * 72 + 32 + quad * 8];
                    OrB[nt] = MFMA16(va0, rbB0, OrB[nt]);
                    OrB[nt] = MFMA16(va1, rbB1, OrB[nt]);
                }
            }
            __syncthreads();
        }

        // ---- epilogue: assemble in RS (wave-private), coalesced b128 stores
        #pragma unroll
        for (int nt = 0; nt < 4; ++nt) {
            bf16x4 ov;
            #pragma unroll
            for (int r = 0; r < 4; ++r) ov[r] = (__bf16)OrA[nt][r];
            *(bf16x4*)&rsrow[nt * 16 + quad * 4] = ov;
        }
        #pragma unroll
        for (int i = 0; i < 2; ++i) {
            const int r = erow + i * 8;
            *(float4*)(rbuf + ((size_t)(n * L_ + qA + r)) * E_ + h * 64 + ec8 * 8) =
                *(const float4*)&RS[(size_t)(w * 16 + r) * 104 + ec8 * 8];
        }
        #pragma unroll
        for (int nt = 0; nt < 4; ++nt) {
            bf16x4 ov;
            #pragma unroll
            for (int r = 0; r < 4; ++r) ov[r] = (__bf16)OrB[nt][r];
            *(bf16x4*)&rsrow[nt * 16 + quad * 4] = ov;
        }
        #pragma unroll
        for (int i = 0; i < 2; ++i) {
            const int r = erow + i * 8;
            *(float4*)(rbuf + ((size_t)(n * L_ + qA + 128 + r)) * E_ + h * 64 + ec8 * 8) =
                *(const float4*)&RS[(size_t)(w * 16 + r) * 104 + ec8 * 8];
        }
    }
}

// ---------------------------------------------------------------------------
// addrel: attnA += rbuf (in place, bf16, b128). ~48 MB of traffic ~= 12 us;
// lets proj keep pure global_load_lds staging.
// ---------------------------------------------------------------------------
__global__ __launch_bounds__(256) void addrel_kernel(
    __bf16* __restrict__ attnA, const __bf16* __restrict__ rbuf)
{
    const size_t i = ((size_t)blockIdx.x * 256 + threadIdx.x) * 8;
    union { float4 f; __bf16 hv[8]; } ua, ur, uo;
    ua.f = *(const float4*)(attnA + i);
    ur.f = *(const float4*)(rbuf + i);
    #pragma unroll
    for (int j = 0; j < 8; ++j)
        uo.hv[j] = (__bf16)((float)ua.hv[j] + (float)ur.hv[j]);
    *(float4*)(attnA + i) = uo.f;
}

// ---------------------------------------------------------------------------
// proj: out (8192 x 1024) f32 = attnA (bf16) @ Wo^T (bf16) + bo.
// 128x128 C tile, BK=64, global_load_lds width-16 staging (round-0 form).
// ---------------------------------------------------------------------------
__global__ __launch_bounds__(256) void proj_kernel(
    const __bf16* __restrict__ A, const __bf16* __restrict__ W,
    const float* __restrict__ bo, float* __restrict__ out)
{
    const int bid = blockIdx.x;
    const int rt = bid >> 3, ct = bid & 7;
    const int r0 = rt * 128, c0 = ct * 128;
    const int t = threadIdx.x, w = t >> 6, lane = t & 63;
    const int quad = lane >> 4, l16 = lane & 15;
    const int wm = w >> 1, wn = w & 1;

    __shared__ __bf16 As[128 * 64];
    __shared__ __bf16 Bs[128 * 64];

    f32x4 acc[16];
    const f32x4 zero4 = {0.f, 0.f, 0.f, 0.f};
    #pragma unroll
    for (int i = 0; i < 16; ++i) acc[i] = zero4;

    const int lrow = lane >> 3, lcg = lane & 7;

    for (int kt = 0; kt < 16; ++kt) {
        const int e0 = kt * 64;
        __syncthreads();
        #pragma unroll
        for (int i = 0; i < 4; ++i) {
            const int chunk = w * 4 + i;
            const int row = chunk * 8 + lrow;
            const __bf16* ga = A + (size_t)(r0 + row) * E_ + e0 + lcg * 8;
            const __bf16* gb = W + (size_t)(c0 + row) * E_ + e0 + lcg * 8;
            __builtin_amdgcn_global_load_lds(
                (const __attribute__((address_space(1))) void*)ga,
                (__attribute__((address_space(3))) void*)&As[chunk * 512], 16, 0, 0);
            __builtin_amdgcn_global_load_lds(
                (const __attribute__((address_space(1))) void*)gb,
                (__attribute__((address_space(3))) void*)&Bs[chunk * 512], 16, 0, 0);
        }
        __syncthreads();
        #pragma unroll
        for (int c = 0; c < 2; ++c) {
            bf16x8 am[4], bn[4];
            #pragma unroll
            for (int i = 0; i < 4; ++i) {
                am[i] = *(const bf16x8*)&As[(wm * 64 + i * 16 + l16) * 64 + c * 32 + quad * 8];
                bn[i] = *(const bf16x8*)&Bs[(wn * 64 + i * 16 + l16) * 64 + c * 32 + quad * 8];
            }
            #pragma unroll
            for (int i = 0; i < 4; ++i)
                #pragma unroll
                for (int j = 0; j < 4; ++j)
                    acc[i * 4 + j] = MFMA16(am[i], bn[j], acc[i * 4 + j]);
        }
    }

    #pragma unroll
    for (int i = 0; i < 4; ++i)
        #pragma unroll
        for (int j = 0; j < 4; ++j) {
            const int col = c0 + wn * 64 + j * 16 + l16;
            const float bb = bo[col];
            #pragma unroll
            for (int r = 0; r < 4; ++r)
                out[(size_t)(r0 + wm * 64 + i * 16 + quad * 4 + r) * E_ + col] =
                    acc[i * 4 + j][r] + bb;
        }
}

// ---------------------------------------------------------------------------
extern "C" void kernel_launch(void* const* d_in, const int* in_sizes, int n_in,
                              void* d_out, int out_size, void* d_ws, size_t ws_size,
                              hipStream_t stream)
{
    const float* x    = (const float*)d_in[0];
    const float* Wq   = (const float*)d_in[1];
    const float* bq   = (const float*)d_in[2];
    const float* Wk   = (const float*)d_in[3];
    const float* bk   = (const float*)d_in[4];
    const float* Wv   = (const float*)d_in[5];
    const float* bv   = (const float*)d_in[6];
    const float* Erel = (const float*)d_in[7];
    const float* Wo   = (const float*)d_in[8];
    const float* bo   = (const float*)d_in[9];
    float* out = (float*)d_out;

    char* p = (char*)d_ws;
    __bf16* qbf   = (__bf16*)p; p += (size_t)N_ * L_ * H_ * D_ * 2;  // 16 MB
    __bf16* kbf   = (__bf16*)p; p += (size_t)N_ * L_ * H_ * D_ * 2;  // scaled K
    __bf16* vbf   = (__bf16*)p; p += (size_t)N_ * L_ * H_ * D_ * 2;
    __bf16* vtrb  = (__bf16*)p; p += (size_t)N_ * L_ * H_ * D_ * 2;  // V^T
    __bf16* attnA = (__bf16*)p; p += (size_t)N_ * L_ * E_ * 2;       // 16 MB
    __bf16* rbuf  = (__bf16*)p; p += (size_t)N_ * L_ * E_ * 2;       // 16 MB
    __bf16* wobf  = (__bf16*)p; p += (size_t)E_ * E_ * 2;            // 2 MB
    __bf16* erbf  = (__bf16*)p; p += (size_t)ER_ROWS * D_ * 2;       // 138 KB (padded)

    prep_kernel<<<1093, 256, 0, stream>>>(Wo, Erel, wobf, erbf);
    qkv_kernel<<<(N_ * L_ * H_) / 64, 256, 0, stream>>>(x, Wq, bq, Wk, bk, Wv, bv,
                                                        qbf, kbf, vbf);
    vtr_kernel<<<N_ * H_ * (L_ / 64), 256, 0, stream>>>(vbf, vtrb);
    attn_kernel<<<1024, 512, 0, stream>>>(qbf, kbf, vtrb, erbf, attnA, rbuf);
    addrel_kernel<<<4096, 256, 0, stream>>>(attnA, rbuf);
    proj_kernel<<<(N_ * L_ / 128) * (E_ / 128), 256, 0, stream>>>(attnA, wobf, bo, out);
}